// Round 8
// baseline (326.819 us; speedup 1.0000x reference)
//
#include <hip/hip_runtime.h>

// BehaviorFluidFlow — wave-per-row, all-register, zero-barrier formulation.
// R8: EXACT R4 structure (best so far, absmax=0.0) with one mechanism change:
// occupancy. (a) the first-tail-channel prefetch is moved to AFTER the pass
// loop (frees 8 VGPRs across the loop's live range; R5/R6 proved prefetch
// depth is neutral), (b) __launch_bounds__(256,5) caps VGPR at <=102 so 5
// waves/SIMD (20 waves/CU) are resident instead of 4 — more decorrelated
// waves to keep the VMEM pipe busy during each wave's compute/LDS phases.
//
//   * all interaction is roll(+/-1) along W; becomes_right[w] == becomes_left[w+sh]
//   * blend coeffs a,b in {0,1} channel-independent -> each pixel is a sum of
//     source pixels (usually exactly one). Track decision channels exactly
//     (dens/fm f32, one-hots+gravity as nibble counters), record provenance
//     (up to 6 sources) and apply it to the 12 passive channels at the end.

#define CCH 20
#define BHW ((size_t)4194304)   // 16*512*512
#define CH  ((size_t)262144)    // 512*512

#define LD8(dst, p) { const float4* _q=(const float4*)(p); float4 _x=_q[0],_y=_q[1]; \
  dst[0]=_x.x;dst[1]=_x.y;dst[2]=_x.z;dst[3]=_x.w;dst[4]=_y.x;dst[5]=_y.y;dst[6]=_y.z;dst[7]=_y.w; }
#define ST8(p, v) { float4* _q=(float4*)(p); _q[0]=make_float4(v[0],v[1],v[2],v[3]); \
  _q[1]=make_float4(v[4],v[5],v[6],v[7]); }

__global__ __launch_bounds__(256, 5) void fluid_wave_kernel(
    const float* __restrict__ world_in,
    const float* __restrict__ rm_in,
    const float* __restrict__ ri_in,
    const float* __restrict__ re_in,
    const float* __restrict__ vf_in,
    const float* __restrict__ dg_in,
    float* __restrict__ out)
{
    // per-wave double-buffered staging row: 512 + 16 pad (s(w)=w+(w>>5) <= 526)
    __shared__ float s_g[4][2][528];

    const int lane = threadIdx.x & 63;
    const int wv   = threadIdx.x >> 6;
    const int row  = (blockIdx.x << 2) + wv;   // b*512 + h
    const int b    = row >> 9;
    const int h    = row & 511;
    const int px0  = lane << 3;

    const size_t srow  = (size_t)row * 512;
    const size_t wrow  = (((size_t)b * CCH) * 512 + h) * 512;
    const size_t vrow0 = (((size_t)b * 2) * 512 + h) * 512;
    const size_t vrow1 = vrow0 + CH;

    const float* win  = world_in + wrow;
    float*       wout = out + wrow;

    // ---- passthrough copies (issued first, overlap with everything) ----
    float t[8];
    LD8(t, ri_in + srow + px0);  ST8(out + 21*BHW + srow + px0, t);
    LD8(t, re_in + srow + px0);  ST8(out + 22*BHW + srow + px0, t);
    LD8(t, vf_in + vrow0 + px0); ST8(out + 23*BHW + vrow0 + px0, t);
    LD8(t, vf_in + vrow1 + px0); ST8(out + 23*BHW + vrow1 + px0, t);

    // ---- load decision state ----
    float rm[8], dgv[8], dens[8], fm[8], nf[8];
    uint32_t code[8], sA[8], sB[8];
    LD8(rm,  rm_in + srow + px0);  ST8(out + 20*BHW + srow + px0, rm);
    LD8(dgv, dg_in + srow + px0);  ST8(out + 25*BHW + srow + px0, dgv);
    LD8(dens, win + 14*CH + px0);
    LD8(fm,   win + 16*CH + px0);

    uint32_t ndgm = 0;
    #pragma unroll
    for (int j = 0; j < 8; ++j) ndgm |= (uint32_t)(dgv[j] <= 0.0f) << j;

    LD8(t, win + 15*CH + px0);   // gravity
    #pragma unroll
    for (int j = 0; j < 8; ++j) code[j] = (uint32_t)(t[j] == 1.0f) << 20;
    LD8(t, win +  0*CH + px0);
    #pragma unroll
    for (int j = 0; j < 8; ++j) code[j] |= (uint32_t)(t[j] == 1.0f);
    LD8(t, win +  3*CH + px0);
    #pragma unroll
    for (int j = 0; j < 8; ++j) code[j] |= (uint32_t)(t[j] == 1.0f) << 4;
    LD8(t, win +  4*CH + px0);
    #pragma unroll
    for (int j = 0; j < 8; ++j) code[j] |= (uint32_t)(t[j] == 1.0f) << 8;
    LD8(t, win + 10*CH + px0);
    #pragma unroll
    for (int j = 0; j < 8; ++j) code[j] |= (uint32_t)(t[j] == 1.0f) << 12;
    LD8(t, win + 11*CH + px0);
    #pragma unroll
    for (int j = 0; j < 8; ++j) code[j] |= (uint32_t)(t[j] == 1.0f) << 16;

    #pragma unroll
    for (int j = 0; j < 8; ++j) {
        sA[j] = 1u | ((uint32_t)(px0 + j) << 4);  // cnt=1, src0=own index
        sB[j] = 0u;
        nf[j] = 0.0f;
    }

    const int lft = (lane + 63) & 63, rgt = (lane + 1) & 63;

    // ---- 10 passes: (elem in {0,3,4,10,11}) x (fall_left, fall_right) ----
    #pragma unroll 1
    for (int ei = 0; ei < 5; ++ei) {
        const int sft = ei * 4;               // nibble slot of this elem
        #pragma unroll
        for (int fi = 0; fi < 2; ++fi) {
            const bool  fl = (fi == 0);       // fall_left first
            const float k  = fl ? 2.0f : -2.0f;

            // edge state of OLD values from neighbor lanes
            const float dL = __shfl(dens[7], lft), dR = __shfl(dens[0], rgt);
            const float fL = __shfl(fm[7],  lft), fR = __shfl(fm[0],  rgt);
            const uint32_t cL = (uint32_t)__shfl((int)code[7], lft);
            const uint32_t cR = (uint32_t)__shfl((int)code[0], rgt);
            const uint32_t AL = (uint32_t)__shfl((int)sA[7], lft);
            const uint32_t AR = (uint32_t)__shfl((int)sA[0], rgt);
            const uint32_t BL = (uint32_t)__shfl((int)sB[7], lft);
            const uint32_t BR = (uint32_t)__shfl((int)sB[0], rgt);

            // a-bits: becomes_left[w], wm = w - sh
            uint32_t am = 0;
            #pragma unroll
            for (int j = 0; j < 8; ++j) {
                float dwm; uint32_t cwm;
                if (fl) { dwm = j ? dens[j-1] : dL;       cwm = j ? code[j-1] : cL; }
                else    { dwm = (j<7) ? dens[j+1] : dR;   cwm = (j<7) ? code[j+1] : cR; }
                const bool fd  = ((rm[j] + fm[j]) + nf[j]) > 0.5f;
                const bool imf = fl ? fd : !fd;
                const bool a = imf
                    && (((code[j] >> sft) & 15u) == 1u)      // is_element
                    && (((ndgm >> j) & 1u) != 0u)            // not_did_gravity
                    && ((dens[j] - dwm) > 0.0f)              // density lower at wm
                    && (((cwm    >> 20) & 15u) == 1u)        // gravity at wm
                    && (((code[j] >> 20) & 15u) == 1u);      // gravity at w
                am |= (uint32_t)a << j;
            }

            // b-bits: becomes_right[w] = a[w+sh]
            const uint32_t aLm = (uint32_t)__shfl((int)am, lft);
            const uint32_t aRm = (uint32_t)__shfl((int)am, rgt);
            const uint32_t bm = fl ? ((am >> 1) | ((aRm & 1u) << 7))
                                   : (((am << 1) & 0xFFu) | ((aLm >> 7) & 1u));

            // blend: new[w] = sel(old[w-sh], old[w], old[w+sh]) (sum if a&b)
            float prD = dL, prF = fL;                    // old[j-1]
            uint32_t prC = cL, prA = AL, prB = BL;
            #pragma unroll
            for (int j = 0; j < 8; ++j) {
                const float    ahD = (j<7) ? dens[j+1] : dR;   // old[j+1]
                const float    ahF = (j<7) ? fm[j+1]   : fR;
                const uint32_t ahC = (j<7) ? code[j+1] : cR;
                const uint32_t ahA = (j<7) ? sA[j+1]   : AR;
                const uint32_t ahB = (j<7) ? sB[j+1]   : BR;
                const float    wmD = fl ? prD : ahD, wpD = fl ? ahD : prD;
                const float    wmF = fl ? prF : ahF, wpF = fl ? ahF : prF;
                const uint32_t wmC = fl ? prC : ahC, wpC = fl ? ahC : prC;
                const uint32_t wmA = fl ? prA : ahA, wpA = fl ? ahA : prA;
                const uint32_t wmB = fl ? prB : ahB, wpB = fl ? ahB : prB;
                const bool a  = (am >> j) & 1u;
                const bool bb = (bm >> j) & 1u;
                if (bb) nf[j] += k;
                prD = dens[j]; prF = fm[j]; prC = code[j]; prA = sA[j]; prB = sB[j];
                if (a & bb) {            // rare double-swap: values SUM
                    dens[j] = wmD + wpD; fm[j] = wmF + wpF; code[j] = wmC + wpC;
                    const uint32_t c1 = wmA & 15u, c2 = wpA & 15u;
                    const uint64_t l1 = ((uint64_t)(wmA >> 4)) | ((uint64_t)wmB << 27);
                    const uint64_t l2 = ((uint64_t)(wpA >> 4)) | ((uint64_t)wpB << 27);
                    uint32_t cnt = c1 + c2; if (cnt > 6u) cnt = 6u;
                    const uint64_t all = l1 | (l2 << (9u * c1));
                    sA[j] = cnt | ((uint32_t)(all & 0x7FFFFFFull) << 4);
                    sB[j] = (uint32_t)((all >> 27) & 0x7FFFFFFull);
                } else if (a) {
                    dens[j] = wmD; fm[j] = wmF; code[j] = wmC; sA[j] = wmA; sB[j] = wmB;
                } else if (bb) {
                    dens[j] = wpD; fm[j] = wpF; code[j] = wpC; sA[j] = wpA; sB[j] = wpB;
                }
            }
        }
    }

    // ---- outputs: tracked channels (frees code[] before the gather) ----
    float o[8];
    #pragma unroll
    for (int j=0;j<8;++j) o[j] = (float)( code[j]        & 15u); ST8(wout +  0*CH + px0, o);
    #pragma unroll
    for (int j=0;j<8;++j) o[j] = (float)((code[j] >>  4) & 15u); ST8(wout +  3*CH + px0, o);
    #pragma unroll
    for (int j=0;j<8;++j) o[j] = (float)((code[j] >>  8) & 15u); ST8(wout +  4*CH + px0, o);
    #pragma unroll
    for (int j=0;j<8;++j) o[j] = (float)((code[j] >> 12) & 15u); ST8(wout + 10*CH + px0, o);
    #pragma unroll
    for (int j=0;j<8;++j) o[j] = (float)((code[j] >> 16) & 15u); ST8(wout + 11*CH + px0, o);
    #pragma unroll
    for (int j=0;j<8;++j) o[j] = (float)((code[j] >> 20) & 15u); ST8(wout + 15*CH + px0, o);
    ST8(wout + 14*CH + px0, dens);
    ST8(wout + 16*CH + px0, nf);

    // ---- passive channels: LDS-staged provenance apply (R4 scheme) ----
    // swizzle s(w) = w + (w>>5): 2-way bank aliasing (free) for stride-8 lanes
    uint32_t multi = 0;
    int sidx0[8];
    #pragma unroll
    for (int j = 0; j < 8; ++j) {
        const uint32_t p = (sA[j] >> 4) & 511u;
        sidx0[j] = (int)(p + (p >> 5));
        multi |= (uint32_t)((sA[j] & 15u) > 1u) << j;
    }
    const int pad = lane >> 2;   // (px0+j)>>5, const for j<8

    static const int GCv[12] = {1,2,5,6,7,8,9,12,13,17,18,19};
    float cur[8], nxt[8];
    LD8(cur, win + 1*CH + px0);     // GCv[0] = 1 (first tail channel)
    #pragma unroll
    for (int g = 0; g < 12; ++g) {
        float* buf = &s_g[wv][g & 1][0];
        #pragma unroll
        for (int j = 0; j < 8; ++j) buf[px0 + pad + j] = cur[j];
        if (g < 11) { LD8(nxt, win + (size_t)GCv[g + 1] * CH + px0); }
        float v[8];
        #pragma unroll
        for (int j = 0; j < 8; ++j) v[j] = buf[sidx0[j]];
        if (multi) {   // rare multi-source pixels (a&b double-swap history)
            #pragma unroll
            for (int j = 0; j < 8; ++j) if ((multi >> j) & 1u) {
                const uint32_t A = sA[j], c = A & 15u, Bv = sB[j];
                uint32_t p1 = (A >> 13) & 511u; float x = v[j] + buf[p1 + (p1 >> 5)];
                if (c > 2u) { uint32_t p2 = (A >> 22) & 511u; x += buf[p2 + (p2 >> 5)];
                  if (c > 3u) { uint32_t p3 = Bv & 511u; x += buf[p3 + (p3 >> 5)];
                    if (c > 4u) { uint32_t p4 = (Bv >> 9) & 511u; x += buf[p4 + (p4 >> 5)];
                      if (c > 5u) { uint32_t p5 = (Bv >> 18) & 511u; x += buf[p5 + (p5 >> 5)]; } } } }
                v[j] = x;
            }
        }
        ST8(wout + (size_t)GCv[g] * CH + px0, v);
        #pragma unroll
        for (int j = 0; j < 8; ++j) cur[j] = nxt[j];
    }
}

extern "C" void kernel_launch(void* const* d_in, const int* in_sizes, int n_in,
                              void* d_out, int out_size, void* d_ws, size_t ws_size,
                              hipStream_t stream) {
    const float* world = (const float*)d_in[0];
    const float* rm    = (const float*)d_in[1];
    const float* ri    = (const float*)d_in[2];
    const float* re    = (const float*)d_in[3];
    const float* vf    = (const float*)d_in[4];
    const float* dg    = (const float*)d_in[5];
    float* out = (float*)d_out;

    dim3 grid(2048), block(256);   // 4 rows per block, 1 wave per row
    fluid_wave_kernel<<<grid, block, 0, stream>>>(world, rm, ri, re, vf, dg, out);
}

// Round 9
// 188.811 us; speedup vs baseline: 1.7309x; 1.7309x over previous
//
#include <hip/hip_runtime.h>

// BehaviorFluidFlow — wave-per-row, all-register, zero-barrier formulation.
// R9: EXACT R4 structure (181 µs, absmax=0.0; R8's launch-bounds cap reverted
// — it spilled: VGPR 48, +340 MB scratch writes). ONE change: the 4
// passthrough copy pairs (ri/re/vf0/vf1, 134 MB of HBM traffic) move from
// the head into the 10-pass compute loop at per-wave staggered points
// ((wv+blockIdx)&3). Mechanism: co-resident blocks run phase-aligned, so
// R4's compute phase (~50 µs aggregate) left the VMEM pipe idle; staggered
// in-loop copies keep HBM drawing during it. (R7's copy-BLOCKS failed
// because they drained early in the launch; these stay in-flight all along.)

#define CCH 20
#define BHW ((size_t)4194304)   // 16*512*512
#define CH  ((size_t)262144)    // 512*512

#define LD8(dst, p) { const float4* _q=(const float4*)(p); float4 _x=_q[0],_y=_q[1]; \
  dst[0]=_x.x;dst[1]=_x.y;dst[2]=_x.z;dst[3]=_x.w;dst[4]=_y.x;dst[5]=_y.y;dst[6]=_y.z;dst[7]=_y.w; }
#define ST8(p, v) { float4* _q=(float4*)(p); _q[0]=make_float4(v[0],v[1],v[2],v[3]); \
  _q[1]=make_float4(v[4],v[5],v[6],v[7]); }

__global__ __launch_bounds__(256) void fluid_wave_kernel(
    const float* __restrict__ world_in,
    const float* __restrict__ rm_in,
    const float* __restrict__ ri_in,
    const float* __restrict__ re_in,
    const float* __restrict__ vf_in,
    const float* __restrict__ dg_in,
    float* __restrict__ out)
{
    // per-wave double-buffered staging row: 512 + 16 pad (s(w)=w+(w>>5) <= 526)
    __shared__ float s_g[4][2][528];

    const int lane = threadIdx.x & 63;
    const int wv   = threadIdx.x >> 6;
    const int row  = (blockIdx.x << 2) + wv;   // b*512 + h
    const int b    = row >> 9;
    const int h    = row & 511;
    const int px0  = lane << 3;

    const size_t srow  = (size_t)row * 512;
    const size_t wrow  = (((size_t)b * CCH) * 512 + h) * 512;
    const size_t vrow0 = (((size_t)b * 2) * 512 + h) * 512;
    const size_t vrow1 = vrow0 + CH;

    const float* win  = world_in + wrow;
    float*       wout = out + wrow;

    // stagger points for the in-loop passthrough copies (wave+block mixed)
    const int stg1 = (wv + (int)blockIdx.x) & 3;          // pass 0..3: ri+re
    const int stg2 = (stg1 + 2) & 3;                      // +2 apart : vf0+vf1

    // ---- load decision state ----
    float t[8];
    float rm[8], dgv[8], dens[8], fm[8], nf[8];
    uint32_t code[8], sA[8], sB[8];
    LD8(rm,  rm_in + srow + px0);  ST8(out + 20*BHW + srow + px0, rm);
    LD8(dgv, dg_in + srow + px0);  ST8(out + 25*BHW + srow + px0, dgv);
    LD8(dens, win + 14*CH + px0);
    LD8(fm,   win + 16*CH + px0);

    uint32_t ndgm = 0;
    #pragma unroll
    for (int j = 0; j < 8; ++j) ndgm |= (uint32_t)(dgv[j] <= 0.0f) << j;

    LD8(t, win + 15*CH + px0);   // gravity
    #pragma unroll
    for (int j = 0; j < 8; ++j) code[j] = (uint32_t)(t[j] == 1.0f) << 20;
    LD8(t, win +  0*CH + px0);
    #pragma unroll
    for (int j = 0; j < 8; ++j) code[j] |= (uint32_t)(t[j] == 1.0f);
    LD8(t, win +  3*CH + px0);
    #pragma unroll
    for (int j = 0; j < 8; ++j) code[j] |= (uint32_t)(t[j] == 1.0f) << 4;
    LD8(t, win +  4*CH + px0);
    #pragma unroll
    for (int j = 0; j < 8; ++j) code[j] |= (uint32_t)(t[j] == 1.0f) << 8;
    LD8(t, win + 10*CH + px0);
    #pragma unroll
    for (int j = 0; j < 8; ++j) code[j] |= (uint32_t)(t[j] == 1.0f) << 12;
    LD8(t, win + 11*CH + px0);
    #pragma unroll
    for (int j = 0; j < 8; ++j) code[j] |= (uint32_t)(t[j] == 1.0f) << 16;

    // prefetch first passive channel (hides HBM latency behind the pass loop)
    float cur[8];
    LD8(cur, win + 1*CH + px0);     // GCv[0] = 1

    #pragma unroll
    for (int j = 0; j < 8; ++j) {
        sA[j] = 1u | ((uint32_t)(px0 + j) << 4);  // cnt=1, src0=own index
        sB[j] = 0u;
        nf[j] = 0.0f;
    }

    const int lft = (lane + 63) & 63, rgt = (lane + 1) & 63;

    // ---- 10 passes: (elem in {0,3,4,10,11}) x (fall_left, fall_right) ----
    #pragma unroll 1
    for (int ei = 0; ei < 5; ++ei) {
        // staggered passthrough copies: keep VMEM drawing during compute
        if (ei == stg1) {
            LD8(t, ri_in + srow + px0);  ST8(out + 21*BHW + srow + px0, t);
            LD8(t, re_in + srow + px0);  ST8(out + 22*BHW + srow + px0, t);
        }
        if (ei == stg2) {
            LD8(t, vf_in + vrow0 + px0); ST8(out + 23*BHW + vrow0 + px0, t);
            LD8(t, vf_in + vrow1 + px0); ST8(out + 23*BHW + vrow1 + px0, t);
        }

        const int sft = ei * 4;               // nibble slot of this elem
        #pragma unroll
        for (int fi = 0; fi < 2; ++fi) {
            const bool  fl = (fi == 0);       // fall_left first
            const float k  = fl ? 2.0f : -2.0f;

            // edge state of OLD values from neighbor lanes
            const float dL = __shfl(dens[7], lft), dR = __shfl(dens[0], rgt);
            const float fL = __shfl(fm[7],  lft), fR = __shfl(fm[0],  rgt);
            const uint32_t cL = (uint32_t)__shfl((int)code[7], lft);
            const uint32_t cR = (uint32_t)__shfl((int)code[0], rgt);
            const uint32_t AL = (uint32_t)__shfl((int)sA[7], lft);
            const uint32_t AR = (uint32_t)__shfl((int)sA[0], rgt);
            const uint32_t BL = (uint32_t)__shfl((int)sB[7], lft);
            const uint32_t BR = (uint32_t)__shfl((int)sB[0], rgt);

            // a-bits: becomes_left[w], wm = w - sh
            uint32_t am = 0;
            #pragma unroll
            for (int j = 0; j < 8; ++j) {
                float dwm; uint32_t cwm;
                if (fl) { dwm = j ? dens[j-1] : dL;       cwm = j ? code[j-1] : cL; }
                else    { dwm = (j<7) ? dens[j+1] : dR;   cwm = (j<7) ? code[j+1] : cR; }
                const bool fd  = ((rm[j] + fm[j]) + nf[j]) > 0.5f;
                const bool imf = fl ? fd : !fd;
                const bool a = imf
                    && (((code[j] >> sft) & 15u) == 1u)      // is_element
                    && (((ndgm >> j) & 1u) != 0u)            // not_did_gravity
                    && ((dens[j] - dwm) > 0.0f)              // density lower at wm
                    && (((cwm    >> 20) & 15u) == 1u)        // gravity at wm
                    && (((code[j] >> 20) & 15u) == 1u);      // gravity at w
                am |= (uint32_t)a << j;
            }

            // b-bits: becomes_right[w] = a[w+sh]
            const uint32_t aLm = (uint32_t)__shfl((int)am, lft);
            const uint32_t aRm = (uint32_t)__shfl((int)am, rgt);
            const uint32_t bm = fl ? ((am >> 1) | ((aRm & 1u) << 7))
                                   : (((am << 1) & 0xFFu) | ((aLm >> 7) & 1u));

            // blend: new[w] = sel(old[w-sh], old[w], old[w+sh]) (sum if a&b)
            float prD = dL, prF = fL;                    // old[j-1]
            uint32_t prC = cL, prA = AL, prB = BL;
            #pragma unroll
            for (int j = 0; j < 8; ++j) {
                const float    ahD = (j<7) ? dens[j+1] : dR;   // old[j+1]
                const float    ahF = (j<7) ? fm[j+1]   : fR;
                const uint32_t ahC = (j<7) ? code[j+1] : cR;
                const uint32_t ahA = (j<7) ? sA[j+1]   : AR;
                const uint32_t ahB = (j<7) ? sB[j+1]   : BR;
                const float    wmD = fl ? prD : ahD, wpD = fl ? ahD : prD;
                const float    wmF = fl ? prF : ahF, wpF = fl ? ahF : prF;
                const uint32_t wmC = fl ? prC : ahC, wpC = fl ? ahC : prC;
                const uint32_t wmA = fl ? prA : ahA, wpA = fl ? ahA : prA;
                const uint32_t wmB = fl ? prB : ahB, wpB = fl ? ahB : prB;
                const bool a  = (am >> j) & 1u;
                const bool bb = (bm >> j) & 1u;
                if (bb) nf[j] += k;
                prD = dens[j]; prF = fm[j]; prC = code[j]; prA = sA[j]; prB = sB[j];
                if (a & bb) {            // rare double-swap: values SUM
                    dens[j] = wmD + wpD; fm[j] = wmF + wpF; code[j] = wmC + wpC;
                    const uint32_t c1 = wmA & 15u, c2 = wpA & 15u;
                    const uint64_t l1 = ((uint64_t)(wmA >> 4)) | ((uint64_t)wmB << 27);
                    const uint64_t l2 = ((uint64_t)(wpA >> 4)) | ((uint64_t)wpB << 27);
                    uint32_t cnt = c1 + c2; if (cnt > 6u) cnt = 6u;
                    const uint64_t all = l1 | (l2 << (9u * c1));
                    sA[j] = cnt | ((uint32_t)(all & 0x7FFFFFFull) << 4);
                    sB[j] = (uint32_t)((all >> 27) & 0x7FFFFFFull);
                } else if (a) {
                    dens[j] = wmD; fm[j] = wmF; code[j] = wmC; sA[j] = wmA; sB[j] = wmB;
                } else if (bb) {
                    dens[j] = wpD; fm[j] = wpF; code[j] = wpC; sA[j] = wpA; sB[j] = wpB;
                }
            }
        }
    }

    // ---- outputs: tracked channels (frees code[] before the gather) ----
    float o[8];
    #pragma unroll
    for (int j=0;j<8;++j) o[j] = (float)( code[j]        & 15u); ST8(wout +  0*CH + px0, o);
    #pragma unroll
    for (int j=0;j<8;++j) o[j] = (float)((code[j] >>  4) & 15u); ST8(wout +  3*CH + px0, o);
    #pragma unroll
    for (int j=0;j<8;++j) o[j] = (float)((code[j] >>  8) & 15u); ST8(wout +  4*CH + px0, o);
    #pragma unroll
    for (int j=0;j<8;++j) o[j] = (float)((code[j] >> 12) & 15u); ST8(wout + 10*CH + px0, o);
    #pragma unroll
    for (int j=0;j<8;++j) o[j] = (float)((code[j] >> 16) & 15u); ST8(wout + 11*CH + px0, o);
    #pragma unroll
    for (int j=0;j<8;++j) o[j] = (float)((code[j] >> 20) & 15u); ST8(wout + 15*CH + px0, o);
    ST8(wout + 14*CH + px0, dens);
    ST8(wout + 16*CH + px0, nf);

    // ---- passive channels: LDS-staged provenance apply (R4 scheme) ----
    // swizzle s(w) = w + (w>>5): 2-way bank aliasing (free) for stride-8 lanes
    uint32_t multi = 0;
    int sidx0[8];
    #pragma unroll
    for (int j = 0; j < 8; ++j) {
        const uint32_t p = (sA[j] >> 4) & 511u;
        sidx0[j] = (int)(p + (p >> 5));
        multi |= (uint32_t)((sA[j] & 15u) > 1u) << j;
    }
    const int pad = lane >> 2;   // (px0+j)>>5, const for j<8

    static const int GCv[12] = {1,2,5,6,7,8,9,12,13,17,18,19};
    float nxt[8];
    #pragma unroll
    for (int g = 0; g < 12; ++g) {
        float* buf = &s_g[wv][g & 1][0];
        #pragma unroll
        for (int j = 0; j < 8; ++j) buf[px0 + pad + j] = cur[j];
        if (g < 11) { LD8(nxt, win + (size_t)GCv[g + 1] * CH + px0); }
        float v[8];
        #pragma unroll
        for (int j = 0; j < 8; ++j) v[j] = buf[sidx0[j]];
        if (multi) {   // rare multi-source pixels (a&b double-swap history)
            #pragma unroll
            for (int j = 0; j < 8; ++j) if ((multi >> j) & 1u) {
                const uint32_t A = sA[j], c = A & 15u, Bv = sB[j];
                uint32_t p1 = (A >> 13) & 511u; float x = v[j] + buf[p1 + (p1 >> 5)];
                if (c > 2u) { uint32_t p2 = (A >> 22) & 511u; x += buf[p2 + (p2 >> 5)];
                  if (c > 3u) { uint32_t p3 = Bv & 511u; x += buf[p3 + (p3 >> 5)];
                    if (c > 4u) { uint32_t p4 = (Bv >> 9) & 511u; x += buf[p4 + (p4 >> 5)];
                      if (c > 5u) { uint32_t p5 = (Bv >> 18) & 511u; x += buf[p5 + (p5 >> 5)]; } } } }
                v[j] = x;
            }
        }
        ST8(wout + (size_t)GCv[g] * CH + px0, v);
        #pragma unroll
        for (int j = 0; j < 8; ++j) cur[j] = nxt[j];
    }
}

extern "C" void kernel_launch(void* const* d_in, const int* in_sizes, int n_in,
                              void* d_out, int out_size, void* d_ws, size_t ws_size,
                              hipStream_t stream) {
    const float* world = (const float*)d_in[0];
    const float* rm    = (const float*)d_in[1];
    const float* ri    = (const float*)d_in[2];
    const float* re    = (const float*)d_in[3];
    const float* vf    = (const float*)d_in[4];
    const float* dg    = (const float*)d_in[5];
    float* out = (float*)d_out;

    dim3 grid(2048), block(256);   // 4 rows per block, 1 wave per row
    fluid_wave_kernel<<<grid, block, 0, stream>>>(world, rm, ri, re, vf, dg, out);
}

// Round 10
// 182.321 us; speedup vs baseline: 1.7925x; 1.0356x over previous
//
#include <hip/hip_runtime.h>

// BehaviorFluidFlow — wave-per-row, all-register, zero-barrier formulation.
// R10: EXACT R4 algorithm (best: 181 µs, absmax=0.0). ONE mechanism change:
// memory-level parallelism. R4's head reused a single t[8] buffer for 6
// decision loads and 4 passthrough pairs -> WAR hazards serialize ~10 HBM
// latencies per wave. Here every concurrent load has a DISTINCT destination
// array: 10 decision loads in flight, then 4 passthrough loads in flight,
// tail ping-pongs two named buffers (no rotation copies). Loads-in-flight
// per wave: head 1-2 -> 10, tail 1 -> 2.

#define CCH 20
#define BHW ((size_t)4194304)   // 16*512*512
#define CH  ((size_t)262144)    // 512*512

#define LD8(dst, p) { const float4* _q=(const float4*)(p); float4 _x=_q[0],_y=_q[1]; \
  dst[0]=_x.x;dst[1]=_x.y;dst[2]=_x.z;dst[3]=_x.w;dst[4]=_y.x;dst[5]=_y.y;dst[6]=_y.z;dst[7]=_y.w; }
#define ST8(p, v) { float4* _q=(float4*)(p); _q[0]=make_float4(v[0],v[1],v[2],v[3]); \
  _q[1]=make_float4(v[4],v[5],v[6],v[7]); }

__global__ __launch_bounds__(256) void fluid_wave_kernel(
    const float* __restrict__ world_in,
    const float* __restrict__ rm_in,
    const float* __restrict__ ri_in,
    const float* __restrict__ re_in,
    const float* __restrict__ vf_in,
    const float* __restrict__ dg_in,
    float* __restrict__ out)
{
    // per-wave double-buffered staging row: 512 + 16 pad (s(w)=w+(w>>5) <= 526)
    __shared__ float s_g[4][2][528];

    const int lane = threadIdx.x & 63;
    const int wv   = threadIdx.x >> 6;
    const int row  = (blockIdx.x << 2) + wv;   // b*512 + h
    const int b    = row >> 9;
    const int h    = row & 511;
    const int px0  = lane << 3;

    const size_t srow  = (size_t)row * 512;
    const size_t wrow  = (((size_t)b * CCH) * 512 + h) * 512;
    const size_t vrow0 = (((size_t)b * 2) * 512 + h) * 512;
    const size_t vrow1 = vrow0 + CH;

    const float* win  = world_in + wrow;
    float*       wout = out + wrow;

    // ---- head: issue ALL 10 decision loads with distinct destinations ----
    float rm[8], dgv[8], dens[8], fm[8];
    float tg[8], e0[8], e3[8], e4[8], e10[8], e11[8];
    LD8(rm,   rm_in + srow + px0);
    LD8(dgv,  dg_in + srow + px0);
    LD8(dens, win + 14*CH + px0);
    LD8(fm,   win + 16*CH + px0);
    LD8(tg,   win + 15*CH + px0);
    LD8(e0,   win +  0*CH + px0);
    LD8(e3,   win +  3*CH + px0);
    LD8(e4,   win +  4*CH + px0);
    LD8(e10,  win + 10*CH + px0);
    LD8(e11,  win + 11*CH + px0);

    // pack decision state (consumes the 6 one-hot/grav arrays, frees 48 regs)
    uint32_t code[8], sA[8], sB[8];
    float nf[8];
    uint32_t ndgm = 0;
    #pragma unroll
    for (int j = 0; j < 8; ++j) {
        code[j] = ((uint32_t)(tg[j]  == 1.0f) << 20)
                |  (uint32_t)(e0[j]  == 1.0f)
                | ((uint32_t)(e3[j]  == 1.0f) << 4)
                | ((uint32_t)(e4[j]  == 1.0f) << 8)
                | ((uint32_t)(e10[j] == 1.0f) << 12)
                | ((uint32_t)(e11[j] == 1.0f) << 16);
        ndgm |= (uint32_t)(dgv[j] <= 0.0f) << j;
        sA[j] = 1u | ((uint32_t)(px0 + j) << 4);  // cnt=1, src0=own index
        sB[j] = 0u;
        nf[j] = 0.0f;
    }
    ST8(out + 20*BHW + srow + px0, rm);
    ST8(out + 25*BHW + srow + px0, dgv);

    // ---- passthrough copies: 4 distinct buffers, 4 loads in flight ----
    {
        float p0[8], p1[8], p2[8], p3[8];
        LD8(p0, ri_in + srow  + px0);
        LD8(p1, re_in + srow  + px0);
        LD8(p2, vf_in + vrow0 + px0);
        LD8(p3, vf_in + vrow1 + px0);
        ST8(out + 21*BHW + srow  + px0, p0);
        ST8(out + 22*BHW + srow  + px0, p1);
        ST8(out + 23*BHW + vrow0 + px0, p2);
        ST8(out + 23*BHW + vrow1 + px0, p3);
    }

    // prefetch first passive channel (hides HBM latency behind the pass loop)
    float curA[8], curB[8];
    LD8(curA, win + 1*CH + px0);     // GCv[0] = 1

    const int lft = (lane + 63) & 63, rgt = (lane + 1) & 63;

    // ---- 10 passes: (elem in {0,3,4,10,11}) x (fall_left, fall_right) ----
    #pragma unroll 1
    for (int ei = 0; ei < 5; ++ei) {
        const int sft = ei * 4;               // nibble slot of this elem
        #pragma unroll
        for (int fi = 0; fi < 2; ++fi) {
            const bool  fl = (fi == 0);       // fall_left first
            const float k  = fl ? 2.0f : -2.0f;

            // edge state of OLD values from neighbor lanes
            const float dL = __shfl(dens[7], lft), dR = __shfl(dens[0], rgt);
            const float fL = __shfl(fm[7],  lft), fR = __shfl(fm[0],  rgt);
            const uint32_t cL = (uint32_t)__shfl((int)code[7], lft);
            const uint32_t cR = (uint32_t)__shfl((int)code[0], rgt);
            const uint32_t AL = (uint32_t)__shfl((int)sA[7], lft);
            const uint32_t AR = (uint32_t)__shfl((int)sA[0], rgt);
            const uint32_t BL = (uint32_t)__shfl((int)sB[7], lft);
            const uint32_t BR = (uint32_t)__shfl((int)sB[0], rgt);

            // a-bits: becomes_left[w], wm = w - sh
            uint32_t am = 0;
            #pragma unroll
            for (int j = 0; j < 8; ++j) {
                float dwm; uint32_t cwm;
                if (fl) { dwm = j ? dens[j-1] : dL;       cwm = j ? code[j-1] : cL; }
                else    { dwm = (j<7) ? dens[j+1] : dR;   cwm = (j<7) ? code[j+1] : cR; }
                const bool fd  = ((rm[j] + fm[j]) + nf[j]) > 0.5f;
                const bool imf = fl ? fd : !fd;
                const bool a = imf
                    && (((code[j] >> sft) & 15u) == 1u)      // is_element
                    && (((ndgm >> j) & 1u) != 0u)            // not_did_gravity
                    && ((dens[j] - dwm) > 0.0f)              // density lower at wm
                    && (((cwm    >> 20) & 15u) == 1u)        // gravity at wm
                    && (((code[j] >> 20) & 15u) == 1u);      // gravity at w
                am |= (uint32_t)a << j;
            }

            // b-bits: becomes_right[w] = a[w+sh]
            const uint32_t aLm = (uint32_t)__shfl((int)am, lft);
            const uint32_t aRm = (uint32_t)__shfl((int)am, rgt);
            const uint32_t bm = fl ? ((am >> 1) | ((aRm & 1u) << 7))
                                   : (((am << 1) & 0xFFu) | ((aLm >> 7) & 1u));

            // blend: new[w] = sel(old[w-sh], old[w], old[w+sh]) (sum if a&b)
            float prD = dL, prF = fL;                    // old[j-1]
            uint32_t prC = cL, prA = AL, prB = BL;
            #pragma unroll
            for (int j = 0; j < 8; ++j) {
                const float    ahD = (j<7) ? dens[j+1] : dR;   // old[j+1]
                const float    ahF = (j<7) ? fm[j+1]   : fR;
                const uint32_t ahC = (j<7) ? code[j+1] : cR;
                const uint32_t ahA = (j<7) ? sA[j+1]   : AR;
                const uint32_t ahB = (j<7) ? sB[j+1]   : BR;
                const float    wmD = fl ? prD : ahD, wpD = fl ? ahD : prD;
                const float    wmF = fl ? prF : ahF, wpF = fl ? ahF : prF;
                const uint32_t wmC = fl ? prC : ahC, wpC = fl ? ahC : prC;
                const uint32_t wmA = fl ? prA : ahA, wpA = fl ? ahA : prA;
                const uint32_t wmB = fl ? prB : ahB, wpB = fl ? ahB : prB;
                const bool a  = (am >> j) & 1u;
                const bool bb = (bm >> j) & 1u;
                if (bb) nf[j] += k;
                prD = dens[j]; prF = fm[j]; prC = code[j]; prA = sA[j]; prB = sB[j];
                if (a & bb) {            // rare double-swap: values SUM
                    dens[j] = wmD + wpD; fm[j] = wmF + wpF; code[j] = wmC + wpC;
                    const uint32_t c1 = wmA & 15u, c2 = wpA & 15u;
                    const uint64_t l1 = ((uint64_t)(wmA >> 4)) | ((uint64_t)wmB << 27);
                    const uint64_t l2 = ((uint64_t)(wpA >> 4)) | ((uint64_t)wpB << 27);
                    uint32_t cnt = c1 + c2; if (cnt > 6u) cnt = 6u;
                    const uint64_t all = l1 | (l2 << (9u * c1));
                    sA[j] = cnt | ((uint32_t)(all & 0x7FFFFFFull) << 4);
                    sB[j] = (uint32_t)((all >> 27) & 0x7FFFFFFull);
                } else if (a) {
                    dens[j] = wmD; fm[j] = wmF; code[j] = wmC; sA[j] = wmA; sB[j] = wmB;
                } else if (bb) {
                    dens[j] = wpD; fm[j] = wpF; code[j] = wpC; sA[j] = wpA; sB[j] = wpB;
                }
            }
        }
    }

    // ---- outputs: tracked channels (frees code[] before the gather) ----
    float o[8];
    #pragma unroll
    for (int j=0;j<8;++j) o[j] = (float)( code[j]        & 15u); ST8(wout +  0*CH + px0, o);
    #pragma unroll
    for (int j=0;j<8;++j) o[j] = (float)((code[j] >>  4) & 15u); ST8(wout +  3*CH + px0, o);
    #pragma unroll
    for (int j=0;j<8;++j) o[j] = (float)((code[j] >>  8) & 15u); ST8(wout +  4*CH + px0, o);
    #pragma unroll
    for (int j=0;j<8;++j) o[j] = (float)((code[j] >> 12) & 15u); ST8(wout + 10*CH + px0, o);
    #pragma unroll
    for (int j=0;j<8;++j) o[j] = (float)((code[j] >> 16) & 15u); ST8(wout + 11*CH + px0, o);
    #pragma unroll
    for (int j=0;j<8;++j) o[j] = (float)((code[j] >> 20) & 15u); ST8(wout + 15*CH + px0, o);
    ST8(wout + 14*CH + px0, dens);
    ST8(wout + 16*CH + px0, nf);

    // ---- passive channels: LDS-staged provenance apply, ping-pong depth-2 ----
    // swizzle s(w) = w + (w>>5): 2-way bank aliasing (free) for stride-8 lanes
    uint32_t multi = 0;
    int sidx0[8];
    #pragma unroll
    for (int j = 0; j < 8; ++j) {
        const uint32_t p = (sA[j] >> 4) & 511u;
        sidx0[j] = (int)(p + (p >> 5));
        multi |= (uint32_t)((sA[j] & 15u) > 1u) << j;
    }
    const int pad = lane >> 2;   // (px0+j)>>5, const for j<8

    static const int GCv[12] = {1,2,5,6,7,8,9,12,13,17,18,19};

#define APPLY_CHANNEL(BUFSEL, CURBUF, GIDX)                                    \
    {                                                                          \
        float* buf = &s_g[wv][BUFSEL][0];                                      \
        _Pragma("unroll")                                                      \
        for (int j = 0; j < 8; ++j) buf[px0 + pad + j] = CURBUF[j];            \
        float v[8];                                                            \
        _Pragma("unroll")                                                      \
        for (int j = 0; j < 8; ++j) v[j] = buf[sidx0[j]];                      \
        if (multi) {                                                           \
            _Pragma("unroll")                                                  \
            for (int j = 0; j < 8; ++j) if ((multi >> j) & 1u) {               \
                const uint32_t A = sA[j], c = A & 15u, Bv = sB[j];             \
                uint32_t p1 = (A >> 13) & 511u;                                \
                float x = v[j] + buf[p1 + (p1 >> 5)];                          \
                if (c > 2u) { uint32_t p2 = (A >> 22) & 511u;                  \
                  x += buf[p2 + (p2 >> 5)];                                    \
                  if (c > 3u) { uint32_t p3 = Bv & 511u;                       \
                    x += buf[p3 + (p3 >> 5)];                                  \
                    if (c > 4u) { uint32_t p4 = (Bv >> 9) & 511u;              \
                      x += buf[p4 + (p4 >> 5)];                                \
                      if (c > 5u) { uint32_t p5 = (Bv >> 18) & 511u;           \
                        x += buf[p5 + (p5 >> 5)]; } } } }                      \
                v[j] = x;                                                      \
            }                                                                  \
        }                                                                      \
        ST8(wout + (size_t)GCv[GIDX] * CH + px0, v);                           \
    }

    #pragma unroll
    for (int g = 0; g < 12; g += 2) {
        // consume curA / prefetch curB, then consume curB / prefetch curA
        if (g + 1 < 12) { LD8(curB, win + (size_t)GCv[g + 1] * CH + px0); }
        APPLY_CHANNEL(0, curA, g)
        if (g + 2 < 12) { LD8(curA, win + (size_t)GCv[g + 2] * CH + px0); }
        if (g + 1 < 12) APPLY_CHANNEL(1, curB, g + 1)
    }
#undef APPLY_CHANNEL
}

extern "C" void kernel_launch(void* const* d_in, const int* in_sizes, int n_in,
                              void* d_out, int out_size, void* d_ws, size_t ws_size,
                              hipStream_t stream) {
    const float* world = (const float*)d_in[0];
    const float* rm    = (const float*)d_in[1];
    const float* ri    = (const float*)d_in[2];
    const float* re    = (const float*)d_in[3];
    const float* vf    = (const float*)d_in[4];
    const float* dg    = (const float*)d_in[5];
    float* out = (float*)d_out;

    dim3 grid(2048), block(256);   // 4 rows per block, 1 wave per row
    fluid_wave_kernel<<<grid, block, 0, stream>>>(world, rm, ri, re, vf, dg, out);
}